// Round 17
// baseline (277.466 us; speedup 1.0000x reference)
//
#include <hip/hip_runtime.h>
#include <float.h>

#define Bn 2
#define Nn 8192
#define Rr 2048
#define Kk 16
#define CIN 64
#define CL 16
#define COUT 128
#define K2c 256
#define GT (Bn*Rr)      // 4096 groups
#define FD (CL+CIN)     // 80
#define KC (Kk*FD)      // 1280
#define MG 4            // mlp groups per block

// ---------------- prep: weight transposes / permute + pts4 packing ----------------
__global__ __launch_bounds__(256) void prep_kernel(
    const float* __restrict__ t1_w, const float* __restrict__ t2_w,
    const float* __restrict__ t3_w, const float* __restrict__ conv_w,
    const float* __restrict__ points,
    float* __restrict__ t1t, float* __restrict__ t2t,
    float* __restrict__ t3t, float* __restrict__ wp,
    float4* __restrict__ pts4)
{
  int i = blockIdx.x * 256 + threadIdx.x;
  if (i < K2c*48) { int j = i / 48, k = i - j*48; t1t[k*K2c + j] = t1_w[i]; }
  if (i < K2c*K2c) { int j = i >> 8, k = i & 255; t2t[k*K2c + j] = t2_w[i]; t3t[k*K2c + j] = t3_w[i]; }
  if (i < COUT*KC) {
    int o = i / KC, ck = i - o*KC;
    int c = ck >> 4, k = ck & 15;
    wp[(k*FD + c)*COUT + o] = conv_w[i];
  }
  if (i < Bn*Nn) {
    float x = points[i*3+0], y = points[i*3+1], z = points[i*3+2];
    // numpy order: sq = (x*x + y*y) + z*z, muls materialized then summed
    float sq = __fadd_rn(__fadd_rn(__fmul_rn(x,x), __fmul_rn(y,y)), __fmul_rn(z,z));
    pts4[i] = make_float4(x, y, z, sq);
  }
}

// ---------------- knn v7: 2 queries/wave on LDS chunks (halves ds_read traffic) ----
// 512 threads = 8 waves, each wave owns 2 queries; one staged float4 feeds both
// queries' d2. Per-query math (d2 chain, tau = 6 rounds over c2, superset
// collection, exact u64 extraction) is byte-identical to v5.1 => selection
// provably unchanged. Grid GT/16 = 256 blocks (1/CU); ptsS 48 KB + coll 16 KB.
__global__ __launch_bounds__(512) void knn_kernel(
    const float4* __restrict__ pts4, const int* __restrict__ rep_idx,
    int* __restrict__ nb_idx, float* __restrict__ p_out,
    float* __restrict__ rep_pos_out)
{
  __shared__ float4 ptsS[3072];                      // 48 KB chunk
  __shared__ unsigned long long coll[8][2][128];     // 16 KB
  int t    = threadIdx.x;
  int lane = t & 63;
  int w    = t >> 6;                  // 0..7
  int gA   = blockIdx.x * 16 + w*2;   // wave owns gA, gA+1 (16 | 2048: same batch)
  int b    = gA >> 11;
  int rA   = gA & 2047;
  int nA   = rep_idx[rA];
  int nB   = rep_idx[rA + 1];
  const float4* pb4 = pts4 + (size_t)b*Nn;
  float4 QA = pb4[nA];
  float4 QB = pb4[nB];

  // ---- pass 1: per-lane top-3 VALUES for both queries over 3 chunks ----
  float a0 = FLT_MAX, a1 = FLT_MAX, a2 = FLT_MAX;
  float b0 = FLT_MAX, b1 = FLT_MAX, b2 = FLT_MAX;
  for (int c = 0; c < 3; c++) {
    int base  = c * 3072;
    int count = (c < 2) ? 3072 : 2048;
    __syncthreads();
    for (int i = t; i < count; i += 512) ptsS[i] = pb4[base + i];
    __syncthreads();
    int iters = count >> 6;
    #pragma unroll 4
    for (int j = 0; j < iters; j++) {
      float4 P = ptsS[j*64 + lane];
      float dotA = __fmaf_rn(QA.z, P.z, __fmaf_rn(QA.y, P.y, __fmul_rn(QA.x, P.x)));
      float d2A  = __fsub_rn(__fadd_rn(QA.w, P.w), __fmul_rn(2.0f, dotA));
      float dotB = __fmaf_rn(QB.z, P.z, __fmaf_rn(QB.y, P.y, __fmul_rn(QB.x, P.x)));
      float d2B  = __fsub_rn(__fadd_rn(QB.w, P.w), __fmul_rn(2.0f, dotB));
      float na2 = __builtin_amdgcn_fmed3f(a1, a2, d2A);
      float na1 = __builtin_amdgcn_fmed3f(a0, a1, d2A);
      float na0 = fminf(a0, d2A);
      a0 = na0; a1 = na1; a2 = na2;
      float nb2 = __builtin_amdgcn_fmed3f(b1, b2, d2B);
      float nb1 = __builtin_amdgcn_fmed3f(b0, b1, d2B);
      float nb0 = fminf(b0, d2B);
      b0 = nb0; b1 = nb1; b2 = nb2;
    }
  }

  // ---- tau per query: 6 rounds of wave-wide min over c2 (>= 18 elems <= tau) ----
  float tauA = FLT_MAX, tauB = FLT_MAX;
  for (int rnd = 0; rnd < 6; rnd++) {
    float m = a2;
    #pragma unroll
    for (int off = 1; off < 64; off <<= 1) m = fminf(m, __shfl_xor(m, off));
    if (a2 == m) a2 = FLT_MAX;
    tauA = m;
  }
  for (int rnd = 0; rnd < 6; rnd++) {
    float m = b2;
    #pragma unroll
    for (int off = 1; off < 64; off <<= 1) m = fminf(m, __shfl_xor(m, off));
    if (b2 == m) b2 = FLT_MAX;
    tauB = m;
  }

  // ---- pass 2: chunk 2 (resident) first, then re-stage 0,1; collect both ----
  int cntA = 0, cntB = 0;
  #pragma unroll
  for (int cc = 0; cc < 3; cc++) {
    int c = (cc == 0) ? 2 : (cc - 1);     // order: 2, 0, 1
    int base  = c * 3072;
    int count = (c < 2) ? 3072 : 2048;
    if (cc != 0) {
      __syncthreads();
      for (int i = t; i < count; i += 512) ptsS[i] = pb4[base + i];
      __syncthreads();
    }
    int iters = count >> 6;
    #pragma unroll 4
    for (int j = 0; j < iters; j++) {
      float4 P = ptsS[j*64 + lane];
      int m = base + j*64 + lane;
      float dotA = __fmaf_rn(QA.z, P.z, __fmaf_rn(QA.y, P.y, __fmul_rn(QA.x, P.x)));
      float d2A  = __fsub_rn(__fadd_rn(QA.w, P.w), __fmul_rn(2.0f, dotA));
      bool prA = (d2A <= tauA);
      unsigned long long maskA = __ballot(prA);
      if (prA) {
        int pos = cntA + (int)__popcll(maskA & ((1ull << lane) - 1ull));
        if (pos < 128) {
          unsigned f = __float_as_uint(d2A);
          unsigned mono = f ^ ((unsigned)((int)f >> 31) | 0x80000000u);
          coll[w][0][pos] = ((unsigned long long)mono << 32) | (unsigned)m;
        }
      }
      cntA += (int)__popcll(maskA);
      float dotB = __fmaf_rn(QB.z, P.z, __fmaf_rn(QB.y, P.y, __fmul_rn(QB.x, P.x)));
      float d2B  = __fsub_rn(__fadd_rn(QB.w, P.w), __fmul_rn(2.0f, dotB));
      bool prB = (d2B <= tauB);
      unsigned long long maskB = __ballot(prB);
      if (prB) {
        int pos = cntB + (int)__popcll(maskB & ((1ull << lane) - 1ull));
        if (pos < 128) {
          unsigned f = __float_as_uint(d2B);
          unsigned mono = f ^ ((unsigned)((int)f >> 31) | 0x80000000u);
          coll[w][1][pos] = ((unsigned long long)mono << 32) | (unsigned)m;
        }
      }
      cntB += (int)__popcll(maskB);
    }
  }
  if (cntA > 128) cntA = 128;
  if (cntB > 128) cntB = 128;

  // ---- final: exact top-17 extraction, query A then B ----
  #pragma unroll
  for (int q = 0; q < 2; q++) {
    int cnt = q ? cntB : cntA;
    int g   = gA + q;
    float qx = q ? QB.x : QA.x;
    float qy = q ? QB.y : QA.y;
    float qz = q ? QB.z : QA.z;
    unsigned long long e1 = (lane < cnt)      ? coll[w][q][lane]      : ~0ull;
    unsigned long long e2 = (lane + 64 < cnt) ? coll[w][q][lane + 64] : ~0ull;
    int out_m = 0;
    for (int rnd = 0; rnd < 17; rnd++) {
      unsigned long long myk = (e1 < e2) ? e1 : e2;
      unsigned long long kmin = myk;
      #pragma unroll
      for (int off = 1; off < 64; off <<= 1) {
        unsigned long long o = __shfl_xor(kmin, off);
        kmin = (o < kmin) ? o : kmin;
      }
      if (rnd >= 1 && lane == rnd - 1) out_m = (int)(kmin & 0xFFFFFFFFull);
      if (kmin == e1) e1 = ~0ull;
      else if (kmin == e2) e2 = ~0ull;
    }
    if (lane < 16) {
      nb_idx[g*Kk + lane] = out_m;
      float4 P = pb4[out_m];
      p_out[(g*Kk + lane)*3 + 0] = __fsub_rn(P.x, qx);
      p_out[(g*Kk + lane)*3 + 1] = __fsub_rn(P.y, qy);
      p_out[(g*Kk + lane)*3 + 2] = __fsub_rn(P.z, qz);
    }
    if (lane < 3) rep_pos_out[g*3 + lane] = (lane == 0 ? qx : (lane == 1 ? qy : qz));
  }
}

// ---------------- mlptf: mlp v6 fused with tf (T stays in LDS) ----------------
// Phase A = mlp v6 verbatim (bit-identical math), epilogue -> T_s in LDS.
// Phase B = tf verbatim, f_s unioned with red (red dead before f_s born).
__device__ __forceinline__ void fma_g(float4& a, float hv, const float4& wv) {
  a.x = fmaf(hv, wv.x, a.x);
  a.y = fmaf(hv, wv.y, a.y);
  a.z = fmaf(hv, wv.z, a.z);
  a.w = fmaf(hv, wv.w, a.w);
}

__global__ __launch_bounds__(256) void mlptf_kernel(
    const float* __restrict__ p,
    const float* __restrict__ t1t, const float* __restrict__ t1_b,
    const float* __restrict__ g1v, const float* __restrict__ b1v,
    const float* __restrict__ t2t, const float* __restrict__ t2_b,
    const float* __restrict__ g2v, const float* __restrict__ b2v,
    const float* __restrict__ t3t, const float* __restrict__ t3_b,
    const float* __restrict__ g3v, const float* __restrict__ b3v,
    const float* __restrict__ features, const int* __restrict__ nb_idx,
    const float* __restrict__ lift_w, const float* __restrict__ lift_b,
    const float* __restrict__ bng, const float* __restrict__ bnb,
    float* __restrict__ Tf)
{
  __shared__ float pf[48][MG];       // 768 B
  __shared__ float hA[K2c][MG];      // 4 KB
  __shared__ float T_s[MG*K2c];      // 4 KB
  __shared__ float uni[MG*KC];       // 20 KB: red (first 4224 floats) then f_s
  __shared__ float ps[MG*48];        // 768 B
  __shared__ int   idxs[64];
  __shared__ float lw[48], lb2[16], lg[16], lo[16];
  int t = threadIdx.x;
  int w = t >> 6, l = t & 63;
  int g0 = blockIdx.x * MG;
  int b = g0 / Rr;                   // 4 | 2048: no batch straddle
  for (int e = t; e < MG*48; e += 256) {
    int g = e / 48, k = e - g*48;
    pf[k][g] = p[(size_t)(g0+g)*48 + k];
    ps[e]    = p[(size_t)g0*48 + e];
  }
  if (t < 64) idxs[t] = nb_idx[g0*16 + t];
  if (t >= 64 && t < 112)  lw[t-64]   = lift_w[t-64];
  if (t >= 112 && t < 128) lb2[t-112] = lift_b[t-112];
  if (t >= 128 && t < 144) lg[t-128]  = bng[t-128];
  if (t >= 144 && t < 160) lo[t-144]  = bnb[t-144];
  __syncthreads();

  float4 acc[MG];

#define LDW(WSRC, K) (*(const float4*)&WSRC[(size_t)(K)*K2c + 4*l])

#define KSTAGE(WSRC, KDIM, HBUF, WB, KK, KNEXT)                        \
  {                                                                    \
    float4 wc = WB;                                                    \
    if ((KNEXT) < KDIM) WB = LDW(WSRC, KNEXT);                         \
    float4 h = *(const float4*)&HBUF[KK][0];                           \
    fma_g(acc[0], h.x, wc); fma_g(acc[1], h.y, wc);                    \
    fma_g(acc[2], h.z, wc); fma_g(acc[3], h.w, wc);                    \
  }

#define KLOOP(WSRC, KDIM, HBUF)                                        \
  {                                                                    \
    _Pragma("unroll")                                                  \
    for (int q = 0; q < MG; q++) acc[q] = make_float4(0.f,0.f,0.f,0.f);\
    float4 wb0 = LDW(WSRC, w);                                         \
    float4 wb1 = (w + 4  < KDIM) ? LDW(WSRC, w + 4)  : wb0;            \
    float4 wb2 = (w + 8  < KDIM) ? LDW(WSRC, w + 8)  : wb0;            \
    float4 wb3 = (w + 12 < KDIM) ? LDW(WSRC, w + 12) : wb0;            \
    for (int k = w; k < KDIM; k += 16) {                               \
      KSTAGE(WSRC, KDIM, HBUF, wb0, k,      k + 16)                    \
      if (k + 4 < KDIM)  KSTAGE(WSRC, KDIM, HBUF, wb1, k + 4,  k + 20) \
      if (k + 8 < KDIM)  KSTAGE(WSRC, KDIM, HBUF, wb2, k + 8,  k + 24) \
      if (k + 12 < KDIM) KSTAGE(WSRC, KDIM, HBUF, wb3, k + 12, k + 28) \
    }                                                                  \
  }

#define WRITE_RED()                                                    \
  {                                                                    \
    _Pragma("unroll")                                                  \
    for (int q = 0; q < MG; q++) {                                     \
      uni[(w*16 + 0*4 + q)*66 + l] = acc[q].x;                         \
      uni[(w*16 + 1*4 + q)*66 + l] = acc[q].y;                         \
      uni[(w*16 + 2*4 + q)*66 + l] = acc[q].z;                         \
      uni[(w*16 + 3*4 + q)*66 + l] = acc[q].w;                         \
    }                                                                  \
  }

#define REDUCE(S)                                                      \
  float4 S = make_float4(0.f,0.f,0.f,0.f);                             \
  {                                                                    \
    int lr = t >> 2, cc = t & 3;                                       \
    _Pragma("unroll")                                                  \
    for (int ww = 0; ww < 4; ww++) {                                   \
      S.x += uni[(ww*16 + cc*4 + 0)*66 + lr];                          \
      S.y += uni[(ww*16 + cc*4 + 1)*66 + lr];                          \
      S.z += uni[(ww*16 + cc*4 + 2)*66 + lr];                          \
      S.w += uni[(ww*16 + cc*4 + 3)*66 + lr];                          \
    }                                                                  \
  }

  // ===== layer 1 (K=48), relu =====
  KLOOP(t1t, 48, pf)
  WRITE_RED()
  __syncthreads();
  {
    REDUCE(s)
    float bb = t1_b[t], gg = g1v[t], oo = b1v[t];
    float4 v;
    v.x = fmaxf(fmaf(s.x + bb, gg, oo), 0.f);
    v.y = fmaxf(fmaf(s.y + bb, gg, oo), 0.f);
    v.z = fmaxf(fmaf(s.z + bb, gg, oo), 0.f);
    v.w = fmaxf(fmaf(s.w + bb, gg, oo), 0.f);
    *(float4*)&hA[t][0] = v;
  }
  __syncthreads();

  // ===== layer 2 (K=256), relu =====
  KLOOP(t2t, K2c, hA)
  WRITE_RED()
  __syncthreads();
  {
    REDUCE(s)
    float bb = t2_b[t], gg = g2v[t], oo = b2v[t];
    float4 v;
    v.x = fmaxf(fmaf(s.x + bb, gg, oo), 0.f);
    v.y = fmaxf(fmaf(s.y + bb, gg, oo), 0.f);
    v.z = fmaxf(fmaf(s.z + bb, gg, oo), 0.f);
    v.w = fmaxf(fmaf(s.w + bb, gg, oo), 0.f);
    *(float4*)&hA[t][0] = v;
  }
  __syncthreads();

  // ===== layer 3 (K=256), no relu -> T_s in LDS =====
  KLOOP(t3t, K2c, hA)
  WRITE_RED()
  __syncthreads();
  {
    REDUCE(s)
    float bb = t3_b[t], gg = g3v[t], oo = b3v[t];
    T_s[0*K2c + t] = fmaf(s.x + bb, gg, oo);
    T_s[1*K2c + t] = fmaf(s.y + bb, gg, oo);
    T_s[2*K2c + t] = fmaf(s.z + bb, gg, oo);
    T_s[3*K2c + t] = fmaf(s.w + bb, gg, oo);
  }
  __syncthreads();   // T_s complete; all red reads done -> uni reusable as f_s

  // ===== phase B: build feat in uni, Tf = T @ feat =====
  {
    int wv = t >> 6, ln = t & 63;
    for (int row = wv; row < 64; row += 4) {
      int gg = row >> 4, k = row & 15;
      uni[gg*KC + k*FD + CL + ln] = features[((size_t)b*Nn + idxs[row])*CIN + ln];
    }
  }
  for (int e = t; e < 1024; e += 256) {
    int gg = e >> 8, rem = e & 255, k = rem >> 4, c = rem & 15;
    float acc1 = ps[gg*48 + k*3 + 0]*lw[c*3+0] + ps[gg*48 + k*3 + 1]*lw[c*3+1]
               + ps[gg*48 + k*3 + 2]*lw[c*3+2] + lb2[c];
    acc1 = acc1*lg[c] + lo[c];
    uni[gg*KC + k*FD + c] = fmaxf(acc1, 0.f);
  }
  __syncthreads();

  {
    int gg = t >> 6;    // wave per group
    int cl = t & 63;
    for (int ci = cl; ci < FD; ci += 64) {
      float fcol[16];
      #pragma unroll
      for (int j = 0; j < 16; j++) fcol[j] = uni[gg*KC + j*FD + ci];
      #pragma unroll
      for (int k = 0; k < 16; k++) {
        float a1 = 0.f;
        #pragma unroll
        for (int j = 0; j < 16; j++) a1 = fmaf(T_s[gg*K2c + k*16 + j], fcol[j], a1);
        Tf[(size_t)(g0+gg)*KC + k*FD + ci] = a1;
      }
    }
  }
#undef KLOOP
#undef KSTAGE
#undef LDW
#undef WRITE_RED
#undef REDUCE
}

// ---------------- gemm: out = Tf(4096x1280) @ Wp(1280x128), split-K=8 ----------------
__global__ __launch_bounds__(256) void gemm_kernel(
    const float* __restrict__ A,    // Tf
    const float* __restrict__ Bm,   // Wp
    float* __restrict__ part)       // [8][GT][COUT]
{
  __shared__ float As[16*36];
  __shared__ float Bs[16*COUT];
  int t = threadIdx.x;
  int m0 = blockIdx.x * 32;
  int ky = blockIdx.y;
  int kbase0 = ky * (KC/8);         // 160
  float acc[4][4];
  #pragma unroll
  for (int i = 0; i < 4; i++)
    #pragma unroll
    for (int j = 0; j < 4; j++) acc[i][j] = 0.f;
  int tn = t & 31, tm = t >> 5;

  for (int kt = 0; kt < KC/8; kt += 16) {
    int kb = kbase0 + kt;
    {
      int kcol = t & 15, row = t >> 4;
      As[kcol*36 + row]      = A[(size_t)(m0+row)*KC + kb + kcol];
      As[kcol*36 + row + 16] = A[(size_t)(m0+row+16)*KC + kb + kcol];
    }
    {
      int o = t & 127, kk2 = t >> 7;
      #pragma unroll
      for (int p4 = 0; p4 < 8; p4++) {
        int kk = kk2 + p4*2;
        Bs[kk*COUT + o] = Bm[(size_t)(kb+kk)*COUT + o];
      }
    }
    __syncthreads();
    #pragma unroll
    for (int kk = 0; kk < 16; kk++) {
      float4 a4 = *(const float4*)&As[kk*36 + tm*4];
      float4 b4 = *(const float4*)&Bs[kk*COUT + tn*4];
      float av[4] = {a4.x, a4.y, a4.z, a4.w};
      float bv[4] = {b4.x, b4.y, b4.z, b4.w};
      #pragma unroll
      for (int i = 0; i < 4; i++)
        #pragma unroll
        for (int j = 0; j < 4; j++) acc[i][j] = fmaf(av[i], bv[j], acc[i][j]);
    }
    __syncthreads();
  }
  #pragma unroll
  for (int i = 0; i < 4; i++) {
    float4 v = make_float4(acc[i][0], acc[i][1], acc[i][2], acc[i][3]);
    *(float4*)&part[((size_t)ky*GT + m0 + tm*4 + i)*COUT + tn*4] = v;
  }
}

// ---------------- reduce: out = sum(part[0..7]) + bias ----------------
__global__ __launch_bounds__(256) void reduce_kernel(
    const float* __restrict__ part, const float* __restrict__ conv_b,
    float* __restrict__ outp)
{
  int i = blockIdx.x*256 + threadIdx.x;
  float4 s = ((const float4*)conv_b)[i & 31];
  #pragma unroll
  for (int w = 0; w < 8; w++) {
    float4 v = ((const float4*)(part + (size_t)w*GT*COUT))[i];
    s.x += v.x; s.y += v.y; s.z += v.z; s.w += v.w;
  }
  ((float4*)outp)[i] = s;
}

extern "C" void kernel_launch(void* const* d_in, const int* in_sizes, int n_in,
                              void* d_out, int out_size, void* d_ws, size_t ws_size,
                              hipStream_t stream) {
  const float* points   = (const float*)d_in[0];
  const float* features = (const float*)d_in[1];
  const float* lift_w   = (const float*)d_in[2];
  const float* lift_b   = (const float*)d_in[3];
  const float* bn_lift_g= (const float*)d_in[4];
  const float* bn_lift_b= (const float*)d_in[5];
  const float* t1_w     = (const float*)d_in[6];
  const float* t1_b     = (const float*)d_in[7];
  const float* bn1_g    = (const float*)d_in[8];
  const float* bn1_b    = (const float*)d_in[9];
  const float* t2_w     = (const float*)d_in[10];
  const float* t2_b     = (const float*)d_in[11];
  const float* bn2_g    = (const float*)d_in[12];
  const float* bn2_b    = (const float*)d_in[13];
  const float* t3_w     = (const float*)d_in[14];
  const float* t3_b     = (const float*)d_in[15];
  const float* bn3_g    = (const float*)d_in[16];
  const float* bn3_b    = (const float*)d_in[17];
  const float* conv_w   = (const float*)d_in[18];
  const float* conv_b   = (const float*)d_in[19];
  const int*   rep_idx  = (const int*)d_in[20];

  char* ws = (char*)d_ws;
  int*    nb   = (int*)   (ws + 0);          // 256 KB
  float*  p    = (float*) (ws + 262144);     // 768 KB
  float*  Tf   = (float*) (ws + 5242880);    // 20 MB
  float*  wp   = (float*) (ws + 26214400);   // 640 KB
  float*  t1t  = (float*) (ws + 26869760);   // 48 KB
  float*  t2t  = (float*) (ws + 26918912);   // 256 KB
  float*  t3t  = (float*) (ws + 27181056);   // 256 KB
  float*  part = (float*) (ws + 33554432);   // 16 MB (8 splits)
  float4* pts4 = (float4*)(ws + 52428800);   // 256 KB

  float* rep_pos = (float*)d_out;
  float* outp    = (float*)d_out + (size_t)GT*3;

  prep_kernel<<<640, 256, 0, stream>>>(t1_w, t2_w, t3_w, conv_w, points,
                                       t1t, t2t, t3t, wp, pts4);
  knn_kernel<<<GT/16, 512, 0, stream>>>(pts4, rep_idx, nb, p, rep_pos);
  mlptf_kernel<<<GT/MG, 256, 0, stream>>>(p, t1t, t1_b, bn1_g, bn1_b,
                                          t2t, t2_b, bn2_g, bn2_b,
                                          t3t, t3_b, bn3_g, bn3_b,
                                          features, nb,
                                          lift_w, lift_b, bn_lift_g, bn_lift_b,
                                          Tf);
  dim3 ggrid(GT/32, 8);
  gemm_kernel<<<ggrid, 256, 0, stream>>>(Tf, wp, part);
  reduce_kernel<<<(GT*COUT/4)/256, 256, 0, stream>>>(part, conv_b, outp);
}

// Round 18
// 220.030 us; speedup vs baseline: 1.2610x; 1.2610x over previous
//
#include <hip/hip_runtime.h>
#include <float.h>

#define Bn 2
#define Nn 8192
#define Rr 2048
#define Kk 16
#define CIN 64
#define CL 16
#define COUT 128
#define K2c 256
#define GT (Bn*Rr)      // 4096 groups
#define FD (CL+CIN)     // 80
#define KC (Kk*FD)      // 1280
#define MG 4            // mlp groups per block

// ---------------- prep: weight transposes / permute + pts4 packing ----------------
__global__ __launch_bounds__(256) void prep_kernel(
    const float* __restrict__ t1_w, const float* __restrict__ t2_w,
    const float* __restrict__ t3_w, const float* __restrict__ conv_w,
    const float* __restrict__ points,
    float* __restrict__ t1t, float* __restrict__ t2t,
    float* __restrict__ t3t, float* __restrict__ wp,
    float4* __restrict__ pts4)
{
  int i = blockIdx.x * 256 + threadIdx.x;
  if (i < K2c*48) { int j = i / 48, k = i - j*48; t1t[k*K2c + j] = t1_w[i]; }
  if (i < K2c*K2c) { int j = i >> 8, k = i & 255; t2t[k*K2c + j] = t2_w[i]; t3t[k*K2c + j] = t3_w[i]; }
  if (i < COUT*KC) {
    int o = i / KC, ck = i - o*KC;
    int c = ck >> 4, k = ck & 15;
    wp[(k*FD + c)*COUT + o] = conv_w[i];
  }
  if (i < Bn*Nn) {
    float x = points[i*3+0], y = points[i*3+1], z = points[i*3+2];
    // numpy order: sq = (x*x + y*y) + z*z, muls materialized then summed
    float sq = __fadd_rn(__fadd_rn(__fmul_rn(x,x), __fmul_rn(y,y)), __fmul_rn(z,z));
    pts4[i] = make_float4(x, y, z, sq);
  }
}

// ---------------- knn v5.1: LDS-chunked two-pass, cheap tau, resident-chunk reuse ----
__global__ __launch_bounds__(512) void knn_kernel(
    const float4* __restrict__ pts4, const int* __restrict__ rep_idx,
    int* __restrict__ nb_idx, float* __restrict__ p_out,
    float* __restrict__ rep_pos_out)
{
  __shared__ float4 ptsS[3072];                    // 48 KB chunk
  __shared__ unsigned long long coll[8][128];      // 8 KB
  int t    = threadIdx.x;
  int lane = t & 63;
  int w    = t >> 6;                 // 0..7
  int g    = blockIdx.x * 8 + w;     // query 0..4095
  int b    = g >> 11;
  int r    = g & 2047;
  int n    = rep_idx[r];
  const float4* pb4 = pts4 + (size_t)b*Nn;
  float4 Q = pb4[n];
  float qx = Q.x, qy = Q.y, qz = Q.z, sqn = Q.w;

  // ---- pass 1: per-lane top-3 VALUES (sorted c0<=c1<=c2) over 3 chunks ----
  float c0 = FLT_MAX, c1 = FLT_MAX, c2 = FLT_MAX;
  for (int c = 0; c < 3; c++) {
    int base  = c * 3072;
    int count = (c < 2) ? 3072 : 2048;
    __syncthreads();
    for (int i = t; i < count; i += 512) ptsS[i] = pb4[base + i];
    __syncthreads();
    int iters = count >> 6;
    #pragma unroll 4
    for (int j = 0; j < iters; j++) {
      float4 P = ptsS[j*64 + lane];
      float dot = __fmaf_rn(qz, P.z, __fmaf_rn(qy, P.y, __fmul_rn(qx, P.x)));
      float d2  = __fsub_rn(__fadd_rn(sqn, P.w), __fmul_rn(2.0f, dot));
      float nc2 = __builtin_amdgcn_fmed3f(c1, c2, d2);
      float nc1 = __builtin_amdgcn_fmed3f(c0, c1, d2);
      float nc0 = fminf(c0, d2);
      c0 = nc0; c1 = nc1; c2 = nc2;
    }
  }

  // ---- tau: 6 rounds of wave-wide min over c2 (6 popped lanes x 3 elems >= 18) ----
  float tau = FLT_MAX;
  for (int rnd = 0; rnd < 6; rnd++) {
    float m = c2;
    #pragma unroll
    for (int off = 1; off < 64; off <<= 1) m = fminf(m, __shfl_xor(m, off));
    if (c2 == m) c2 = FLT_MAX;
    tau = m;
  }

  // ---- pass 2: chunk 2 (resident) first, then re-stage chunks 0,1 ----
  int cnt = 0;
  #pragma unroll
  for (int cc = 0; cc < 3; cc++) {
    int c = (cc == 0) ? 2 : (cc - 1);     // order: 2, 0, 1
    int base  = c * 3072;
    int count = (c < 2) ? 3072 : 2048;
    if (cc != 0) {
      __syncthreads();   // all waves done reading previous chunk
      for (int i = t; i < count; i += 512) ptsS[i] = pb4[base + i];
      __syncthreads();
    }
    int iters = count >> 6;
    #pragma unroll 4
    for (int j = 0; j < iters; j++) {
      float4 P = ptsS[j*64 + lane];
      float dot = __fmaf_rn(qz, P.z, __fmaf_rn(qy, P.y, __fmul_rn(qx, P.x)));
      float d2  = __fsub_rn(__fadd_rn(sqn, P.w), __fmul_rn(2.0f, dot));
      bool pr = (d2 <= tau);
      unsigned long long mask = __ballot(pr);
      if (pr) {
        int pos = cnt + (int)__popcll(mask & ((1ull << lane) - 1ull));
        if (pos < 128) {
          unsigned f = __float_as_uint(d2);
          unsigned mono = f ^ ((unsigned)((int)f >> 31) | 0x80000000u);
          coll[w][pos] = ((unsigned long long)mono << 32) | (unsigned)(base + j*64 + lane);
        }
      }
      cnt += (int)__popcll(mask);
    }
  }
  if (cnt > 128) cnt = 128;

  // ---- final: exact top-17 extraction over <=128 unique keys ----
  unsigned long long e1 = (lane < cnt)      ? coll[w][lane]      : ~0ull;
  unsigned long long e2 = (lane + 64 < cnt) ? coll[w][lane + 64] : ~0ull;
  int out_m = 0;
  for (int rnd = 0; rnd < 17; rnd++) {
    unsigned long long myk = (e1 < e2) ? e1 : e2;
    unsigned long long kmin = myk;
    #pragma unroll
    for (int off = 1; off < 64; off <<= 1) {
      unsigned long long o = __shfl_xor(kmin, off);
      kmin = (o < kmin) ? o : kmin;
    }
    if (rnd >= 1 && lane == rnd - 1) out_m = (int)(kmin & 0xFFFFFFFFull);
    if (kmin == e1) e1 = ~0ull;
    else if (kmin == e2) e2 = ~0ull;
  }

  if (lane < 16) {
    nb_idx[g*Kk + lane] = out_m;
    float4 P = pb4[out_m];
    p_out[(g*Kk + lane)*3 + 0] = __fsub_rn(P.x, qx);
    p_out[(g*Kk + lane)*3 + 1] = __fsub_rn(P.y, qy);
    p_out[(g*Kk + lane)*3 + 2] = __fsub_rn(P.z, qz);
  }
  if (lane < 3) rep_pos_out[g*3 + lane] = (lane == 0 ? qx : (lane == 1 ? qy : qz));
}

// ---------------- mlp v6: MG=4, depth-4 weight prefetch (covers L2 latency) ----------------
__device__ __forceinline__ void fma_g(float4& a, float hv, const float4& wv) {
  a.x = fmaf(hv, wv.x, a.x);
  a.y = fmaf(hv, wv.y, a.y);
  a.z = fmaf(hv, wv.z, a.z);
  a.w = fmaf(hv, wv.w, a.w);
}

__global__ __launch_bounds__(256) void mlp_kernel(
    const float* __restrict__ p,
    const float* __restrict__ t1t, const float* __restrict__ t1_b,
    const float* __restrict__ g1v, const float* __restrict__ b1v,
    const float* __restrict__ t2t, const float* __restrict__ t2_b,
    const float* __restrict__ g2v, const float* __restrict__ b2v,
    const float* __restrict__ t3t, const float* __restrict__ t3_b,
    const float* __restrict__ g3v, const float* __restrict__ b3v,
    float* __restrict__ T_out)
{
  __shared__ float pf[48][MG];       // 768 B
  __shared__ float hA[K2c][MG];      // 4 KB
  __shared__ float red[4*16*66];     // 16.9 KB: red[(w*16 + comp*4 + q)*66 + lane]
  int t = threadIdx.x;
  int w = t >> 6, l = t & 63;
  int g0 = blockIdx.x * MG;
  for (int e = t; e < MG*48; e += 256) {
    int g = e / 48, k = e - g*48;
    pf[k][g] = p[(size_t)(g0+g)*48 + k];
  }
  __syncthreads();

  float4 acc[MG];   // acc[q] = group q over cols 4l..4l+3

#define LDW(WSRC, K) (*(const float4*)&WSRC[(size_t)(K)*K2c + 4*l])

#define KSTAGE(WSRC, KDIM, HBUF, WB, KK, KNEXT)                        \
  {                                                                    \
    float4 wc = WB;                                                    \
    if ((KNEXT) < KDIM) WB = LDW(WSRC, KNEXT);                         \
    float4 h = *(const float4*)&HBUF[KK][0];                           \
    fma_g(acc[0], h.x, wc); fma_g(acc[1], h.y, wc);                    \
    fma_g(acc[2], h.z, wc); fma_g(acc[3], h.w, wc);                    \
  }

#define KLOOP(WSRC, KDIM, HBUF)                                        \
  {                                                                    \
    _Pragma("unroll")                                                  \
    for (int q = 0; q < MG; q++) acc[q] = make_float4(0.f,0.f,0.f,0.f);\
    float4 wb0 = LDW(WSRC, w);                                         \
    float4 wb1 = (w + 4  < KDIM) ? LDW(WSRC, w + 4)  : wb0;            \
    float4 wb2 = (w + 8  < KDIM) ? LDW(WSRC, w + 8)  : wb0;            \
    float4 wb3 = (w + 12 < KDIM) ? LDW(WSRC, w + 12) : wb0;            \
    for (int k = w; k < KDIM; k += 16) {                               \
      KSTAGE(WSRC, KDIM, HBUF, wb0, k,      k + 16)                    \
      if (k + 4 < KDIM)  KSTAGE(WSRC, KDIM, HBUF, wb1, k + 4,  k + 20) \
      if (k + 8 < KDIM)  KSTAGE(WSRC, KDIM, HBUF, wb2, k + 8,  k + 24) \
      if (k + 12 < KDIM) KSTAGE(WSRC, KDIM, HBUF, wb3, k + 12, k + 28) \
    }                                                                  \
  }

#define WRITE_RED()                                                    \
  {                                                                    \
    _Pragma("unroll")                                                  \
    for (int q = 0; q < MG; q++) {                                     \
      red[(w*16 + 0*4 + q)*66 + l] = acc[q].x;                         \
      red[(w*16 + 1*4 + q)*66 + l] = acc[q].y;                         \
      red[(w*16 + 2*4 + q)*66 + l] = acc[q].z;                         \
      red[(w*16 + 3*4 + q)*66 + l] = acc[q].w;                         \
    }                                                                  \
  }

#define REDUCE(S)                                                      \
  float4 S = make_float4(0.f,0.f,0.f,0.f);                             \
  {                                                                    \
    int lr = t >> 2, cc = t & 3;                                       \
    _Pragma("unroll")                                                  \
    for (int ww = 0; ww < 4; ww++) {                                   \
      S.x += red[(ww*16 + cc*4 + 0)*66 + lr];                          \
      S.y += red[(ww*16 + cc*4 + 1)*66 + lr];                          \
      S.z += red[(ww*16 + cc*4 + 2)*66 + lr];                          \
      S.w += red[(ww*16 + cc*4 + 3)*66 + lr];                          \
    }                                                                  \
  }

  // ===== layer 1 (K=48), relu =====
  KLOOP(t1t, 48, pf)
  WRITE_RED()
  __syncthreads();
  {
    REDUCE(s)
    float bb = t1_b[t], gg = g1v[t], oo = b1v[t];
    float4 v;
    v.x = fmaxf(fmaf(s.x + bb, gg, oo), 0.f);
    v.y = fmaxf(fmaf(s.y + bb, gg, oo), 0.f);
    v.z = fmaxf(fmaf(s.z + bb, gg, oo), 0.f);
    v.w = fmaxf(fmaf(s.w + bb, gg, oo), 0.f);
    *(float4*)&hA[t][0] = v;
  }
  __syncthreads();

  // ===== layer 2 (K=256), relu =====
  KLOOP(t2t, K2c, hA)
  WRITE_RED()
  __syncthreads();
  {
    REDUCE(s)
    float bb = t2_b[t], gg = g2v[t], oo = b2v[t];
    float4 v;
    v.x = fmaxf(fmaf(s.x + bb, gg, oo), 0.f);
    v.y = fmaxf(fmaf(s.y + bb, gg, oo), 0.f);
    v.z = fmaxf(fmaf(s.z + bb, gg, oo), 0.f);
    v.w = fmaxf(fmaf(s.w + bb, gg, oo), 0.f);
    *(float4*)&hA[t][0] = v;
  }
  __syncthreads();

  // ===== layer 3 (K=256), no relu, to global =====
  KLOOP(t3t, K2c, hA)
  WRITE_RED()
  __syncthreads();
  {
    REDUCE(s)
    float bb = t3_b[t], gg = g3v[t], oo = b3v[t];
    T_out[(size_t)(g0+0)*K2c + t] = fmaf(s.x + bb, gg, oo);
    T_out[(size_t)(g0+1)*K2c + t] = fmaf(s.y + bb, gg, oo);
    T_out[(size_t)(g0+2)*K2c + t] = fmaf(s.z + bb, gg, oo);
    T_out[(size_t)(g0+3)*K2c + t] = fmaf(s.w + bb, gg, oo);
  }
#undef KLOOP
#undef KSTAGE
#undef LDW
#undef WRITE_RED
#undef REDUCE
}

// ---------------- tf (fused feat), 4 groups/block ----------------
__global__ __launch_bounds__(256) void tf_kernel(
    const float* __restrict__ T_in, const float* __restrict__ features,
    const float* __restrict__ p, const int* __restrict__ nb_idx,
    const float* __restrict__ lift_w, const float* __restrict__ lift_b,
    const float* __restrict__ bng, const float* __restrict__ bnb,
    float* __restrict__ Tf)
{
  __shared__ float T_s[4*K2c];    // 4 KB
  __shared__ float f_s[4*KC];     // 20 KB
  __shared__ float ps[4*48];      // 768 B
  __shared__ int   idxs[64];      // 256 B
  __shared__ float lw[48], lb2[16], lg[16], lo[16];
  int t = threadIdx.x;
  int g0 = blockIdx.x * 4;
  int b = g0 / Rr;                // 4 | 2048: block never straddles batches
  for (int e = t; e < 4*K2c; e += 256) T_s[e] = T_in[(size_t)g0*K2c + e];
  if (t >= 32 && t < 224) {
    int e = t - 32;               // 192 threads cover ps
    ps[e] = p[(size_t)g0*48 + e];
  }
  if (t < 64) idxs[t] = nb_idx[g0*16 + t];
  if (t >= 64 && t < 112)  lw[t-64]   = lift_w[t-64];
  if (t >= 112 && t < 128) lb2[t-112] = lift_b[t-112];
  if (t >= 224 && t < 240) lg[t-224]  = bng[t-224];
  if (t >= 240)            lo[t-240]  = bnb[t-240];
  __syncthreads();

  // gather neighbor features: 64 rows of 64
  {
    int wv = t >> 6, ln = t & 63;
    for (int row = wv; row < 64; row += 4) {
      int gg = row >> 4, k = row & 15;
      f_s[gg*KC + k*FD + CL + ln] = features[((size_t)b*Nn + idxs[row])*CIN + ln];
    }
  }
  // lifted BN+ReLU: 4*16*16 = 1024 elements
  for (int e = t; e < 1024; e += 256) {
    int gg = e >> 8, rem = e & 255, k = rem >> 4, c = rem & 15;
    float acc = ps[gg*48 + k*3 + 0]*lw[c*3+0] + ps[gg*48 + k*3 + 1]*lw[c*3+1]
              + ps[gg*48 + k*3 + 2]*lw[c*3+2] + lb2[c];
    acc = acc*lg[c] + lo[c];
    f_s[gg*KC + k*FD + c] = fmaxf(acc, 0.f);
  }
  __syncthreads();

  int gg = t >> 6;    // wave per group
  int cl = t & 63;
  for (int ci = cl; ci < FD; ci += 64) {
    float fcol[16];
    #pragma unroll
    for (int j = 0; j < 16; j++) fcol[j] = f_s[gg*KC + j*FD + ci];
    #pragma unroll
    for (int k = 0; k < 16; k++) {
      float acc = 0.f;
      #pragma unroll
      for (int j = 0; j < 16; j++) acc = fmaf(T_s[gg*K2c + k*16 + j], fcol[j], acc);
      Tf[(size_t)(g0+gg)*KC + k*FD + ci] = acc;
    }
  }
}

// ---------------- gemm: out = Tf(4096x1280) @ Wp(1280x128), split-K=8 ----------------
__global__ __launch_bounds__(256) void gemm_kernel(
    const float* __restrict__ A,    // Tf
    const float* __restrict__ Bm,   // Wp
    float* __restrict__ part)       // [8][GT][COUT]
{
  __shared__ float As[16*36];
  __shared__ float Bs[16*COUT];
  int t = threadIdx.x;
  int m0 = blockIdx.x * 32;
  int ky = blockIdx.y;
  int kbase0 = ky * (KC/8);         // 160
  float acc[4][4];
  #pragma unroll
  for (int i = 0; i < 4; i++)
    #pragma unroll
    for (int j = 0; j < 4; j++) acc[i][j] = 0.f;
  int tn = t & 31, tm = t >> 5;

  for (int kt = 0; kt < KC/8; kt += 16) {
    int kb = kbase0 + kt;
    {
      int kcol = t & 15, row = t >> 4;
      As[kcol*36 + row]      = A[(size_t)(m0+row)*KC + kb + kcol];
      As[kcol*36 + row + 16] = A[(size_t)(m0+row+16)*KC + kb + kcol];
    }
    {
      int o = t & 127, kk2 = t >> 7;
      #pragma unroll
      for (int p4 = 0; p4 < 8; p4++) {
        int kk = kk2 + p4*2;
        Bs[kk*COUT + o] = Bm[(size_t)(kb+kk)*COUT + o];
      }
    }
    __syncthreads();
    #pragma unroll
    for (int kk = 0; kk < 16; kk++) {
      float4 a4 = *(const float4*)&As[kk*36 + tm*4];
      float4 b4 = *(const float4*)&Bs[kk*COUT + tn*4];
      float av[4] = {a4.x, a4.y, a4.z, a4.w};
      float bv[4] = {b4.x, b4.y, b4.z, b4.w};
      #pragma unroll
      for (int i = 0; i < 4; i++)
        #pragma unroll
        for (int j = 0; j < 4; j++) acc[i][j] = fmaf(av[i], bv[j], acc[i][j]);
    }
    __syncthreads();
  }
  #pragma unroll
  for (int i = 0; i < 4; i++) {
    float4 v = make_float4(acc[i][0], acc[i][1], acc[i][2], acc[i][3]);
    *(float4*)&part[((size_t)ky*GT + m0 + tm*4 + i)*COUT + tn*4] = v;
  }
}

// ---------------- reduce: out = sum(part[0..7]) + bias ----------------
__global__ __launch_bounds__(256) void reduce_kernel(
    const float* __restrict__ part, const float* __restrict__ conv_b,
    float* __restrict__ outp)
{
  int i = blockIdx.x*256 + threadIdx.x;
  float4 s = ((const float4*)conv_b)[i & 31];
  #pragma unroll
  for (int w = 0; w < 8; w++) {
    float4 v = ((const float4*)(part + (size_t)w*GT*COUT))[i];
    s.x += v.x; s.y += v.y; s.z += v.z; s.w += v.w;
  }
  ((float4*)outp)[i] = s;
}

extern "C" void kernel_launch(void* const* d_in, const int* in_sizes, int n_in,
                              void* d_out, int out_size, void* d_ws, size_t ws_size,
                              hipStream_t stream) {
  const float* points   = (const float*)d_in[0];
  const float* features = (const float*)d_in[1];
  const float* lift_w   = (const float*)d_in[2];
  const float* lift_b   = (const float*)d_in[3];
  const float* bn_lift_g= (const float*)d_in[4];
  const float* bn_lift_b= (const float*)d_in[5];
  const float* t1_w     = (const float*)d_in[6];
  const float* t1_b     = (const float*)d_in[7];
  const float* bn1_g    = (const float*)d_in[8];
  const float* bn1_b    = (const float*)d_in[9];
  const float* t2_w     = (const float*)d_in[10];
  const float* t2_b     = (const float*)d_in[11];
  const float* bn2_g    = (const float*)d_in[12];
  const float* bn2_b    = (const float*)d_in[13];
  const float* t3_w     = (const float*)d_in[14];
  const float* t3_b     = (const float*)d_in[15];
  const float* bn3_g    = (const float*)d_in[16];
  const float* bn3_b    = (const float*)d_in[17];
  const float* conv_w   = (const float*)d_in[18];
  const float* conv_b   = (const float*)d_in[19];
  const int*   rep_idx  = (const int*)d_in[20];

  char* ws = (char*)d_ws;
  int*    nb   = (int*)   (ws + 0);          // 256 KB
  float*  p    = (float*) (ws + 262144);     // 768 KB
  float*  T    = (float*) (ws + 1048576);    // 4 MB
  float*  Tf   = (float*) (ws + 5242880);    // 20 MB
  float*  wp   = (float*) (ws + 26214400);   // 640 KB
  float*  t1t  = (float*) (ws + 26869760);   // 48 KB
  float*  t2t  = (float*) (ws + 26918912);   // 256 KB
  float*  t3t  = (float*) (ws + 27181056);   // 256 KB
  float*  part = (float*) (ws + 33554432);   // 16 MB (8 splits)
  float4* pts4 = (float4*)(ws + 52428800);   // 256 KB

  float* rep_pos = (float*)d_out;
  float* outp    = (float*)d_out + (size_t)GT*3;

  prep_kernel<<<640, 256, 0, stream>>>(t1_w, t2_w, t3_w, conv_w, points,
                                       t1t, t2t, t3t, wp, pts4);
  knn_kernel<<<GT/8, 512, 0, stream>>>(pts4, rep_idx, nb, p, rep_pos);
  mlp_kernel<<<GT/MG, 256, 0, stream>>>(p, t1t, t1_b, bn1_g, bn1_b,
                                        t2t, t2_b, bn2_g, bn2_b,
                                        t3t, t3_b, bn3_g, bn3_b, T);
  tf_kernel<<<GT/4, 256, 0, stream>>>(T, features, p, nb,
                                      lift_w, lift_b, bn_lift_g, bn_lift_b, Tf);
  dim3 ggrid(GT/32, 8);
  gemm_kernel<<<ggrid, 256, 0, stream>>>(Tf, wp, part);
  reduce_kernel<<<(GT*COUT/4)/256, 256, 0, stream>>>(part, conv_b, outp);
}

// Round 21
// 218.816 us; speedup vs baseline: 1.2680x; 1.0055x over previous
//
#include <hip/hip_runtime.h>
#include <float.h>

#define Bn 2
#define Nn 8192
#define Rr 2048
#define Kk 16
#define CIN 64
#define CL 16
#define COUT 128
#define K2c 256
#define GT (Bn*Rr)      // 4096 groups
#define FD (CL+CIN)     // 80
#define KC (Kk*FD)      // 1280
#define MG 4            // mlp groups per block

// ---------------- prep: weight transposes / permute + pts4 packing ----------------
__global__ __launch_bounds__(256) void prep_kernel(
    const float* __restrict__ t1_w, const float* __restrict__ t2_w,
    const float* __restrict__ t3_w, const float* __restrict__ conv_w,
    const float* __restrict__ points,
    float* __restrict__ t1t, float* __restrict__ t2t,
    float* __restrict__ t3t, float* __restrict__ wp,
    float4* __restrict__ pts4)
{
  int i = blockIdx.x * 256 + threadIdx.x;
  if (i < K2c*48) { int j = i / 48, k = i - j*48; t1t[k*K2c + j] = t1_w[i]; }
  if (i < K2c*K2c) { int j = i >> 8, k = i & 255; t2t[k*K2c + j] = t2_w[i]; t3t[k*K2c + j] = t3_w[i]; }
  if (i < COUT*KC) {
    int o = i / KC, ck = i - o*KC;
    int c = ck >> 4, k = ck & 15;
    wp[(k*FD + c)*COUT + o] = conv_w[i];
  }
  if (i < Bn*Nn) {
    float x = points[i*3+0], y = points[i*3+1], z = points[i*3+2];
    // numpy order: sq = (x*x + y*y) + z*z, muls materialized then summed
    float sq = __fadd_rn(__fadd_rn(__fmul_rn(x,x), __fmul_rn(y,y)), __fmul_rn(z,z));
    pts4[i] = make_float4(x, y, z, sq);
  }
}

// ---------------- knn v5.2: v5.1 selection (proven) on 4x2048 chunks ----------------
// Selection machinery byte-identical to the verified v5.1 (depth-3 med3/min
// cache, tau = 6 wave-min pops over c2, 128-entry cap, exact u64 extraction).
// Only chunk geometry changed: 4 chunks of 2048 (32 KB) -> LDS 40 KB ->
// 3 blocks/CU = 24 waves/CU (vs 16). Candidate->lane mapping is m&63 in both
// layouts (bases are multiples of 64), so per-lane minima, tau, and the
// survivor set are bit-identical; extraction is order-insensitive.
__global__ __launch_bounds__(512) void knn_kernel(
    const float4* __restrict__ pts4, const int* __restrict__ rep_idx,
    int* __restrict__ nb_idx, float* __restrict__ p_out,
    float* __restrict__ rep_pos_out)
{
  __shared__ float4 ptsS[2048];                    // 32 KB chunk
  __shared__ unsigned long long coll[8][128];      // 8 KB
  int t    = threadIdx.x;
  int lane = t & 63;
  int w    = t >> 6;                 // 0..7
  int g    = blockIdx.x * 8 + w;     // query 0..4095
  int b    = g >> 11;
  int r    = g & 2047;
  int n    = rep_idx[r];
  const float4* pb4 = pts4 + (size_t)b*Nn;
  float4 Q = pb4[n];
  float qx = Q.x, qy = Q.y, qz = Q.z, sqn = Q.w;

  // ---- pass 1: per-lane top-3 VALUES (sorted c0<=c1<=c2) over 4 chunks ----
  float c0 = FLT_MAX, c1 = FLT_MAX, c2 = FLT_MAX;
  for (int c = 0; c < 4; c++) {
    int base = c * 2048;
    __syncthreads();
    for (int i = t; i < 2048; i += 512) ptsS[i] = pb4[base + i];
    __syncthreads();
    #pragma unroll 4
    for (int j = 0; j < 32; j++) {
      float4 P = ptsS[j*64 + lane];
      float dot = __fmaf_rn(qz, P.z, __fmaf_rn(qy, P.y, __fmul_rn(qx, P.x)));
      float d2  = __fsub_rn(__fadd_rn(sqn, P.w), __fmul_rn(2.0f, dot));
      float nc2 = __builtin_amdgcn_fmed3f(c1, c2, d2);
      float nc1 = __builtin_amdgcn_fmed3f(c0, c1, d2);
      float nc0 = fminf(c0, d2);
      c0 = nc0; c1 = nc1; c2 = nc2;
    }
  }

  // ---- tau: 6 rounds of wave-wide min over c2 (6 popped lanes x 3 elems >= 18) ----
  float tau = FLT_MAX;
  for (int rnd = 0; rnd < 6; rnd++) {
    float m = c2;
    #pragma unroll
    for (int off = 1; off < 64; off <<= 1) m = fminf(m, __shfl_xor(m, off));
    if (c2 == m) c2 = FLT_MAX;
    tau = m;
  }

  // ---- pass 2: chunk 3 (resident) first, then re-stage 0,1,2 ----
  int cnt = 0;
  #pragma unroll
  for (int cc = 0; cc < 4; cc++) {
    int c = (cc == 0) ? 3 : (cc - 1);     // order: 3, 0, 1, 2
    int base = c * 2048;
    if (cc != 0) {
      __syncthreads();   // all waves done reading previous chunk
      for (int i = t; i < 2048; i += 512) ptsS[i] = pb4[base + i];
      __syncthreads();
    }
    #pragma unroll 4
    for (int j = 0; j < 32; j++) {
      float4 P = ptsS[j*64 + lane];
      float dot = __fmaf_rn(qz, P.z, __fmaf_rn(qy, P.y, __fmul_rn(qx, P.x)));
      float d2  = __fsub_rn(__fadd_rn(sqn, P.w), __fmul_rn(2.0f, dot));
      bool pr = (d2 <= tau);
      unsigned long long mask = __ballot(pr);
      if (pr) {
        int pos = cnt + (int)__popcll(mask & ((1ull << lane) - 1ull));
        if (pos < 128) {
          unsigned f = __float_as_uint(d2);
          unsigned mono = f ^ ((unsigned)((int)f >> 31) | 0x80000000u);
          coll[w][pos] = ((unsigned long long)mono << 32) | (unsigned)(base + j*64 + lane);
        }
      }
      cnt += (int)__popcll(mask);
    }
  }
  if (cnt > 128) cnt = 128;

  // ---- final: exact top-17 extraction over <=128 unique keys ----
  unsigned long long e1 = (lane < cnt)      ? coll[w][lane]      : ~0ull;
  unsigned long long e2 = (lane + 64 < cnt) ? coll[w][lane + 64] : ~0ull;
  int out_m = 0;
  for (int rnd = 0; rnd < 17; rnd++) {
    unsigned long long myk = (e1 < e2) ? e1 : e2;
    unsigned long long kmin = myk;
    #pragma unroll
    for (int off = 1; off < 64; off <<= 1) {
      unsigned long long o = __shfl_xor(kmin, off);
      kmin = (o < kmin) ? o : kmin;
    }
    if (rnd >= 1 && lane == rnd - 1) out_m = (int)(kmin & 0xFFFFFFFFull);
    if (kmin == e1) e1 = ~0ull;
    else if (kmin == e2) e2 = ~0ull;
  }

  if (lane < 16) {
    nb_idx[g*Kk + lane] = out_m;
    float4 P = pb4[out_m];
    p_out[(g*Kk + lane)*3 + 0] = __fsub_rn(P.x, qx);
    p_out[(g*Kk + lane)*3 + 1] = __fsub_rn(P.y, qy);
    p_out[(g*Kk + lane)*3 + 2] = __fsub_rn(P.z, qz);
  }
  if (lane < 3) rep_pos_out[g*3 + lane] = (lane == 0 ? qx : (lane == 1 ? qy : qz));
}

// ---------------- mlp v6: MG=4, depth-4 weight prefetch (covers L2 latency) ----------------
__device__ __forceinline__ void fma_g(float4& a, float hv, const float4& wv) {
  a.x = fmaf(hv, wv.x, a.x);
  a.y = fmaf(hv, wv.y, a.y);
  a.z = fmaf(hv, wv.z, a.z);
  a.w = fmaf(hv, wv.w, a.w);
}

__global__ __launch_bounds__(256) void mlp_kernel(
    const float* __restrict__ p,
    const float* __restrict__ t1t, const float* __restrict__ t1_b,
    const float* __restrict__ g1v, const float* __restrict__ b1v,
    const float* __restrict__ t2t, const float* __restrict__ t2_b,
    const float* __restrict__ g2v, const float* __restrict__ b2v,
    const float* __restrict__ t3t, const float* __restrict__ t3_b,
    const float* __restrict__ g3v, const float* __restrict__ b3v,
    float* __restrict__ T_out)
{
  __shared__ float pf[48][MG];       // 768 B
  __shared__ float hA[K2c][MG];      // 4 KB
  __shared__ float red[4*16*66];     // 16.9 KB: red[(w*16 + comp*4 + q)*66 + lane]
  int t = threadIdx.x;
  int w = t >> 6, l = t & 63;
  int g0 = blockIdx.x * MG;
  for (int e = t; e < MG*48; e += 256) {
    int g = e / 48, k = e - g*48;
    pf[k][g] = p[(size_t)(g0+g)*48 + k];
  }
  __syncthreads();

  float4 acc[MG];   // acc[q] = group q over cols 4l..4l+3

#define LDW(WSRC, K) (*(const float4*)&WSRC[(size_t)(K)*K2c + 4*l])

#define KSTAGE(WSRC, KDIM, HBUF, WB, KK, KNEXT)                        \
  {                                                                    \
    float4 wc = WB;                                                    \
    if ((KNEXT) < KDIM) WB = LDW(WSRC, KNEXT);                         \
    float4 h = *(const float4*)&HBUF[KK][0];                           \
    fma_g(acc[0], h.x, wc); fma_g(acc[1], h.y, wc);                    \
    fma_g(acc[2], h.z, wc); fma_g(acc[3], h.w, wc);                    \
  }

#define KLOOP(WSRC, KDIM, HBUF)                                        \
  {                                                                    \
    _Pragma("unroll")                                                  \
    for (int q = 0; q < MG; q++) acc[q] = make_float4(0.f,0.f,0.f,0.f);\
    float4 wb0 = LDW(WSRC, w);                                         \
    float4 wb1 = (w + 4  < KDIM) ? LDW(WSRC, w + 4)  : wb0;            \
    float4 wb2 = (w + 8  < KDIM) ? LDW(WSRC, w + 8)  : wb0;            \
    float4 wb3 = (w + 12 < KDIM) ? LDW(WSRC, w + 12) : wb0;            \
    for (int k = w; k < KDIM; k += 16) {                               \
      KSTAGE(WSRC, KDIM, HBUF, wb0, k,      k + 16)                    \
      if (k + 4 < KDIM)  KSTAGE(WSRC, KDIM, HBUF, wb1, k + 4,  k + 20) \
      if (k + 8 < KDIM)  KSTAGE(WSRC, KDIM, HBUF, wb2, k + 8,  k + 24) \
      if (k + 12 < KDIM) KSTAGE(WSRC, KDIM, HBUF, wb3, k + 12, k + 28) \
    }                                                                  \
  }

#define WRITE_RED()                                                    \
  {                                                                    \
    _Pragma("unroll")                                                  \
    for (int q = 0; q < MG; q++) {                                     \
      red[(w*16 + 0*4 + q)*66 + l] = acc[q].x;                         \
      red[(w*16 + 1*4 + q)*66 + l] = acc[q].y;                         \
      red[(w*16 + 2*4 + q)*66 + l] = acc[q].z;                         \
      red[(w*16 + 3*4 + q)*66 + l] = acc[q].w;                         \
    }                                                                  \
  }

#define REDUCE(S)                                                      \
  float4 S = make_float4(0.f,0.f,0.f,0.f);                             \
  {                                                                    \
    int lr = t >> 2, cc = t & 3;                                       \
    _Pragma("unroll")                                                  \
    for (int ww = 0; ww < 4; ww++) {                                   \
      S.x += red[(ww*16 + cc*4 + 0)*66 + lr];                          \
      S.y += red[(ww*16 + cc*4 + 1)*66 + lr];                          \
      S.z += red[(ww*16 + cc*4 + 2)*66 + lr];                          \
      S.w += red[(ww*16 + cc*4 + 3)*66 + lr];                          \
    }                                                                  \
  }

  // ===== layer 1 (K=48), relu =====
  KLOOP(t1t, 48, pf)
  WRITE_RED()
  __syncthreads();
  {
    REDUCE(s)
    float bb = t1_b[t], gg = g1v[t], oo = b1v[t];
    float4 v;
    v.x = fmaxf(fmaf(s.x + bb, gg, oo), 0.f);
    v.y = fmaxf(fmaf(s.y + bb, gg, oo), 0.f);
    v.z = fmaxf(fmaf(s.z + bb, gg, oo), 0.f);
    v.w = fmaxf(fmaf(s.w + bb, gg, oo), 0.f);
    *(float4*)&hA[t][0] = v;
  }
  __syncthreads();

  // ===== layer 2 (K=256), relu =====
  KLOOP(t2t, K2c, hA)
  WRITE_RED()
  __syncthreads();
  {
    REDUCE(s)
    float bb = t2_b[t], gg = g2v[t], oo = b2v[t];
    float4 v;
    v.x = fmaxf(fmaf(s.x + bb, gg, oo), 0.f);
    v.y = fmaxf(fmaf(s.y + bb, gg, oo), 0.f);
    v.z = fmaxf(fmaf(s.z + bb, gg, oo), 0.f);
    v.w = fmaxf(fmaf(s.w + bb, gg, oo), 0.f);
    *(float4*)&hA[t][0] = v;
  }
  __syncthreads();

  // ===== layer 3 (K=256), no relu, to global =====
  KLOOP(t3t, K2c, hA)
  WRITE_RED()
  __syncthreads();
  {
    REDUCE(s)
    float bb = t3_b[t], gg = g3v[t], oo = b3v[t];
    T_out[(size_t)(g0+0)*K2c + t] = fmaf(s.x + bb, gg, oo);
    T_out[(size_t)(g0+1)*K2c + t] = fmaf(s.y + bb, gg, oo);
    T_out[(size_t)(g0+2)*K2c + t] = fmaf(s.z + bb, gg, oo);
    T_out[(size_t)(g0+3)*K2c + t] = fmaf(s.w + bb, gg, oo);
  }
#undef KLOOP
#undef KSTAGE
#undef LDW
#undef WRITE_RED
#undef REDUCE
}

// ---------------- tf (fused feat), 4 groups/block ----------------
__global__ __launch_bounds__(256) void tf_kernel(
    const float* __restrict__ T_in, const float* __restrict__ features,
    const float* __restrict__ p, const int* __restrict__ nb_idx,
    const float* __restrict__ lift_w, const float* __restrict__ lift_b,
    const float* __restrict__ bng, const float* __restrict__ bnb,
    float* __restrict__ Tf)
{
  __shared__ float T_s[4*K2c];    // 4 KB
  __shared__ float f_s[4*KC];     // 20 KB
  __shared__ float ps[4*48];      // 768 B
  __shared__ int   idxs[64];      // 256 B
  __shared__ float lw[48], lb2[16], lg[16], lo[16];
  int t = threadIdx.x;
  int g0 = blockIdx.x * 4;
  int b = g0 / Rr;                // 4 | 2048: block never straddles batches
  for (int e = t; e < 4*K2c; e += 256) T_s[e] = T_in[(size_t)g0*K2c + e];
  if (t >= 32 && t < 224) {
    int e = t - 32;               // 192 threads cover ps
    ps[e] = p[(size_t)g0*48 + e];
  }
  if (t < 64) idxs[t] = nb_idx[g0*16 + t];
  if (t >= 64 && t < 112)  lw[t-64]   = lift_w[t-64];
  if (t >= 112 && t < 128) lb2[t-112] = lift_b[t-112];
  if (t >= 224 && t < 240) lg[t-224]  = bng[t-224];
  if (t >= 240)            lo[t-240]  = bnb[t-240];
  __syncthreads();

  // gather neighbor features: 64 rows of 64
  {
    int wv = t >> 6, ln = t & 63;
    for (int row = wv; row < 64; row += 4) {
      int gg = row >> 4, k = row & 15;
      f_s[gg*KC + k*FD + CL + ln] = features[((size_t)b*Nn + idxs[row])*CIN + ln];
    }
  }
  // lifted BN+ReLU: 4*16*16 = 1024 elements
  for (int e = t; e < 1024; e += 256) {
    int gg = e >> 8, rem = e & 255, k = rem >> 4, c = rem & 15;
    float acc = ps[gg*48 + k*3 + 0]*lw[c*3+0] + ps[gg*48 + k*3 + 1]*lw[c*3+1]
              + ps[gg*48 + k*3 + 2]*lw[c*3+2] + lb2[c];
    acc = acc*lg[c] + lo[c];
    f_s[gg*KC + k*FD + c] = fmaxf(acc, 0.f);
  }
  __syncthreads();

  int gg = t >> 6;    // wave per group
  int cl = t & 63;
  for (int ci = cl; ci < FD; ci += 64) {
    float fcol[16];
    #pragma unroll
    for (int j = 0; j < 16; j++) fcol[j] = f_s[gg*KC + j*FD + ci];
    #pragma unroll
    for (int k = 0; k < 16; k++) {
      float acc = 0.f;
      #pragma unroll
      for (int j = 0; j < 16; j++) acc = fmaf(T_s[gg*K2c + k*16 + j], fcol[j], acc);
      Tf[(size_t)(g0+gg)*KC + k*FD + ci] = acc;
    }
  }
}

// ---------------- gemm: out = Tf(4096x1280) @ Wp(1280x128), split-K=8 ----------------
__global__ __launch_bounds__(256) void gemm_kernel(
    const float* __restrict__ A,    // Tf
    const float* __restrict__ Bm,   // Wp
    float* __restrict__ part)       // [8][GT][COUT]
{
  __shared__ float As[16*36];
  __shared__ float Bs[16*COUT];
  int t = threadIdx.x;
  int m0 = blockIdx.x * 32;
  int ky = blockIdx.y;
  int kbase0 = ky * (KC/8);         // 160
  float acc[4][4];
  #pragma unroll
  for (int i = 0; i < 4; i++)
    #pragma unroll
    for (int j = 0; j < 4; j++) acc[i][j] = 0.f;
  int tn = t & 31, tm = t >> 5;

  for (int kt = 0; kt < KC/8; kt += 16) {
    int kb = kbase0 + kt;
    {
      int kcol = t & 15, row = t >> 4;
      As[kcol*36 + row]      = A[(size_t)(m0+row)*KC + kb + kcol];
      As[kcol*36 + row + 16] = A[(size_t)(m0+row+16)*KC + kb + kcol];
    }
    {
      int o = t & 127, kk2 = t >> 7;
      #pragma unroll
      for (int p4 = 0; p4 < 8; p4++) {
        int kk = kk2 + p4*2;
        Bs[kk*COUT + o] = Bm[(size_t)(kb+kk)*COUT + o];
      }
    }
    __syncthreads();
    #pragma unroll
    for (int kk = 0; kk < 16; kk++) {
      float4 a4 = *(const float4*)&As[kk*36 + tm*4];
      float4 b4 = *(const float4*)&Bs[kk*COUT + tn*4];
      float av[4] = {a4.x, a4.y, a4.z, a4.w};
      float bv[4] = {b4.x, b4.y, b4.z, b4.w};
      #pragma unroll
      for (int i = 0; i < 4; i++)
        #pragma unroll
        for (int j = 0; j < 4; j++) acc[i][j] = fmaf(av[i], bv[j], acc[i][j]);
    }
    __syncthreads();
  }
  #pragma unroll
  for (int i = 0; i < 4; i++) {
    float4 v = make_float4(acc[i][0], acc[i][1], acc[i][2], acc[i][3]);
    *(float4*)&part[((size_t)ky*GT + m0 + tm*4 + i)*COUT + tn*4] = v;
  }
}

// ---------------- reduce: out = sum(part[0..7]) + bias ----------------
__global__ __launch_bounds__(256) void reduce_kernel(
    const float* __restrict__ part, const float* __restrict__ conv_b,
    float* __restrict__ outp)
{
  int i = blockIdx.x*256 + threadIdx.x;
  float4 s = ((const float4*)conv_b)[i & 31];
  #pragma unroll
  for (int w = 0; w < 8; w++) {
    float4 v = ((const float4*)(part + (size_t)w*GT*COUT))[i];
    s.x += v.x; s.y += v.y; s.z += v.z; s.w += v.w;
  }
  ((float4*)outp)[i] = s;
}

extern "C" void kernel_launch(void* const* d_in, const int* in_sizes, int n_in,
                              void* d_out, int out_size, void* d_ws, size_t ws_size,
                              hipStream_t stream) {
  const float* points   = (const float*)d_in[0];
  const float* features = (const float*)d_in[1];
  const float* lift_w   = (const float*)d_in[2];
  const float* lift_b   = (const float*)d_in[3];
  const float* bn_lift_g= (const float*)d_in[4];
  const float* bn_lift_b= (const float*)d_in[5];
  const float* t1_w     = (const float*)d_in[6];
  const float* t1_b     = (const float*)d_in[7];
  const float* bn1_g    = (const float*)d_in[8];
  const float* bn1_b    = (const float*)d_in[9];
  const float* t2_w     = (const float*)d_in[10];
  const float* t2_b     = (const float*)d_in[11];
  const float* bn2_g    = (const float*)d_in[12];
  const float* bn2_b    = (const float*)d_in[13];
  const float* t3_w     = (const float*)d_in[14];
  const float* t3_b     = (const float*)d_in[15];
  const float* bn3_g    = (const float*)d_in[16];
  const float* bn3_b    = (const float*)d_in[17];
  const float* conv_w   = (const float*)d_in[18];
  const float* conv_b   = (const float*)d_in[19];
  const int*   rep_idx  = (const int*)d_in[20];

  char* ws = (char*)d_ws;
  int*    nb   = (int*)   (ws + 0);          // 256 KB
  float*  p    = (float*) (ws + 262144);     // 768 KB
  float*  T    = (float*) (ws + 1048576);    // 4 MB
  float*  Tf   = (float*) (ws + 5242880);    // 20 MB
  float*  wp   = (float*) (ws + 26214400);   // 640 KB
  float*  t1t  = (float*) (ws + 26869760);   // 48 KB
  float*  t2t  = (float*) (ws + 26918912);   // 256 KB
  float*  t3t  = (float*) (ws + 27181056);   // 256 KB
  float*  part = (float*) (ws + 33554432);   // 16 MB (8 splits)
  float4* pts4 = (float4*)(ws + 52428800);   // 256 KB

  float* rep_pos = (float*)d_out;
  float* outp    = (float*)d_out + (size_t)GT*3;

  prep_kernel<<<640, 256, 0, stream>>>(t1_w, t2_w, t3_w, conv_w, points,
                                       t1t, t2t, t3t, wp, pts4);
  knn_kernel<<<GT/8, 512, 0, stream>>>(pts4, rep_idx, nb, p, rep_pos);
  mlp_kernel<<<GT/MG, 256, 0, stream>>>(p, t1t, t1_b, bn1_g, bn1_b,
                                        t2t, t2_b, bn2_g, bn2_b,
                                        t3t, t3_b, bn3_g, bn3_b, T);
  tf_kernel<<<GT/4, 256, 0, stream>>>(T, features, p, nb,
                                      lift_w, lift_b, bn_lift_g, bn_lift_b, Tf);
  dim3 ggrid(GT/32, 8);
  gemm_kernel<<<ggrid, 256, 0, stream>>>(Tf, wp, part);
  reduce_kernel<<<(GT*COUT/4)/256, 256, 0, stream>>>(part, conv_b, outp);
}